// Round 3
// baseline (49.690 us; speedup 1.0000x reference)
//
#include <hip/hip_runtime.h>

// Segment-sum via gather (round 3).
// r1: scatter-atomics = 449us (L2-atomic-bound). r2: hist+gather = 43.3us.
// r3: NT load/store hints (all traffic is single-touch), 2-wide unrolled
// gather loop (independent float4 loads), int4-vectorized hist.
// Ideal traffic ~194MiB -> ~31us at 6.3 TB/s.

#define CAP 32          // slot capacity per segment; Poisson(2) tail beyond 32 ~ 1e-26
#define N_SEG 16384
#define DDIM 1024

typedef __attribute__((ext_vector_type(4))) float f4;
typedef __attribute__((ext_vector_type(4))) int i4;

__global__ void hist_fill(const int* __restrict__ tags, int n_rows,
                          int* __restrict__ counts,
                          unsigned short* __restrict__ slots) {
    int r4 = (blockIdx.x * blockDim.x + threadIdx.x) * 4;
    if (r4 + 3 < n_rows) {
        i4 t = *reinterpret_cast<const i4*>(tags + r4);
        #pragma unroll
        for (int j = 0; j < 4; ++j) {
            int tag = t[j];
            int pos = atomicAdd(&counts[tag], 1);
            if (pos < CAP) slots[(long)tag * CAP + pos] = (unsigned short)(r4 + j);
        }
    } else {
        for (int r = r4; r < n_rows; ++r) {
            int tag = tags[r];
            int pos = atomicAdd(&counts[tag], 1);
            if (pos < CAP) slots[(long)tag * CAP + pos] = (unsigned short)r;
        }
    }
}

__global__ void gather_sum(const float* __restrict__ data,
                           const int* __restrict__ tags,
                           const int* __restrict__ counts,
                           const unsigned short* __restrict__ slots,
                           float* __restrict__ out,
                           int n_rows) {
    int s = blockIdx.x;                 // segment id, one block per output row
    int col = threadIdx.x * 4;          // 256 threads x float4 = 1024 cols
    int k = counts[s];
    f4 acc = {0.f, 0.f, 0.f, 0.f};

    if (k <= CAP) {
        const unsigned short* sl = slots + (long)s * CAP;
        int j = 0;
        for (; j + 2 <= k; j += 2) {
            int r0 = sl[j], r1 = sl[j + 1];
            f4 v0 = __builtin_nontemporal_load(
                reinterpret_cast<const f4*>(data + (long)r0 * DDIM + col));
            f4 v1 = __builtin_nontemporal_load(
                reinterpret_cast<const f4*>(data + (long)r1 * DDIM + col));
            acc += v0 + v1;
        }
        if (j < k) {
            int r0 = sl[j];
            acc += __builtin_nontemporal_load(
                reinterpret_cast<const f4*>(data + (long)r0 * DDIM + col));
        }
    } else {
        // Overflow fallback (deterministic, essentially never taken): slots
        // hold an arbitrary subset, so recompute the whole segment by scanning
        // all tags (L2-resident broadcast reads).
        for (int r = 0; r < n_rows; ++r) {
            if (tags[r] == s) {
                f4 v = *reinterpret_cast<const f4*>(data + (long)r * DDIM + col);
                acc += v;
            }
        }
    }
    __builtin_nontemporal_store(acc, reinterpret_cast<f4*>(out + (long)s * DDIM + col));
}

// Safety-net scatter kernel (used only if ws_size is too small for the index).
__global__ void combine_scatter_add(const float* __restrict__ data,
                                    const int* __restrict__ tags,
                                    float* __restrict__ out,
                                    long total_elems) {
    long stride = (long)gridDim.x * blockDim.x * 4L;
    for (long i = ((long)blockIdx.x * blockDim.x + threadIdx.x) * 4L;
         i < total_elems; i += stride) {
        float4 v = *reinterpret_cast<const float4*>(data + i);
        long row = i >> 10;
        int col = (int)(i & 1023);
        int tag = tags[row];
        float* dst = out + ((long)tag << 10) + col;
        atomicAdd(dst + 0, v.x);
        atomicAdd(dst + 1, v.y);
        atomicAdd(dst + 2, v.z);
        atomicAdd(dst + 3, v.w);
    }
}

extern "C" void kernel_launch(void* const* d_in, const int* in_sizes, int n_in,
                              void* d_out, int out_size, void* d_ws, size_t ws_size,
                              hipStream_t stream) {
    const float* data = (const float*)d_in[0];
    const int* tags = (const int*)d_in[1];
    float* out = (float*)d_out;

    long total = (long)in_sizes[0];   // 33554432
    int n_rows = in_sizes[1];         // 32768

    size_t counts_bytes = (size_t)N_SEG * sizeof(int);                 // 64 KiB
    size_t slots_bytes = (size_t)N_SEG * CAP * sizeof(unsigned short); // 1 MiB
    size_t need = counts_bytes + slots_bytes;

    if (ws_size < need) {
        hipMemsetAsync(d_out, 0, (size_t)out_size * sizeof(float), stream);
        combine_scatter_add<<<2048, 256, 0, stream>>>(data, tags, out, total);
        return;
    }

    int* counts = (int*)d_ws;
    unsigned short* slots = (unsigned short*)((char*)d_ws + counts_bytes);

    hipMemsetAsync(counts, 0, counts_bytes, stream);

    hist_fill<<<(n_rows / 4 + 255) / 256, 256, 0, stream>>>(tags, n_rows, counts, slots);

    gather_sum<<<N_SEG, 256, 0, stream>>>(data, tags, counts, slots, out, n_rows);
}

// Round 4
// 42.743 us; speedup vs baseline: 1.1625x; 1.1625x over previous
//
#include <hip/hip_runtime.h>

// Segment-sum via gather (round 4).
// r1 scatter-atomics: 449us (L2-atomic-bound). r2 hist+gather: 43.3us.
// r3 NT-hints+unroll: 49.7us REGRESSION -> reverted (NT bypasses L2; 4KiB
// per-block chunks want L2 aggregation).
// r4 = r2 structure + register-prefetched slot ids in gather (one 16B load
// yields 8 row indices -> the 8 float4 data loads issue independently,
// instead of a dependent u16-load -> data-load chain per row).

#define CAP 32          // slot capacity per segment; Poisson(2) tail beyond 32 ~ 1e-26
#define N_SEG 16384
#define DDIM 1024

typedef __attribute__((ext_vector_type(4))) float f4;
typedef __attribute__((ext_vector_type(4))) int i4;

__global__ void hist_fill(const int* __restrict__ tags, int n_rows,
                          int* __restrict__ counts,
                          unsigned short* __restrict__ slots) {
    int r = blockIdx.x * blockDim.x + threadIdx.x;
    if (r < n_rows) {
        int t = tags[r];
        int pos = atomicAdd(&counts[t], 1);
        if (pos < CAP) slots[(long)t * CAP + pos] = (unsigned short)r;
    }
}

__global__ void gather_sum(const float* __restrict__ data,
                           const int* __restrict__ tags,
                           const int* __restrict__ counts,
                           const unsigned short* __restrict__ slots,
                           float* __restrict__ out,
                           int n_rows) {
    int s = blockIdx.x;                 // segment id, one block per output row
    int col = threadIdx.x * 4;          // 256 threads x float4 = 1024 cols
    int k = counts[s];
    f4 acc = {0.f, 0.f, 0.f, 0.f};

    if (k <= CAP) {
        // Slot list for this segment: 32 u16 = 64B = 4 i4 words, 8 ids/word.
        const i4* sp = reinterpret_cast<const i4*>(slots + (long)s * CAP);
        int done = 0;
        #pragma unroll
        for (int w = 0; w < 4; ++w) {
            if (done >= k) break;                   // wave-uniform branch
            i4 word = sp[w];                        // 8 slot ids in registers
            #pragma unroll
            for (int e = 0; e < 4; ++e) {
                int pair = word[e];
                int r0 = pair & 0xFFFF;
                int r1 = (pair >> 16) & 0xFFFF;
                if (done < k) {
                    acc += *reinterpret_cast<const f4*>(data + (long)r0 * DDIM + col);
                    ++done;
                }
                if (done < k) {
                    acc += *reinterpret_cast<const f4*>(data + (long)r1 * DDIM + col);
                    ++done;
                }
            }
        }
    } else {
        // Overflow fallback (deterministic, essentially never taken): slots
        // hold an arbitrary subset, so recompute the whole segment by scanning
        // all tags (L2-resident broadcast reads).
        for (int r = 0; r < n_rows; ++r) {
            if (tags[r] == s) {
                acc += *reinterpret_cast<const f4*>(data + (long)r * DDIM + col);
            }
        }
    }
    *reinterpret_cast<f4*>(out + (long)s * DDIM + col) = acc;
}

// Safety-net scatter kernel (used only if ws_size is too small for the index).
__global__ void combine_scatter_add(const float* __restrict__ data,
                                    const int* __restrict__ tags,
                                    float* __restrict__ out,
                                    long total_elems) {
    long stride = (long)gridDim.x * blockDim.x * 4L;
    for (long i = ((long)blockIdx.x * blockDim.x + threadIdx.x) * 4L;
         i < total_elems; i += stride) {
        float4 v = *reinterpret_cast<const float4*>(data + i);
        long row = i >> 10;
        int col = (int)(i & 1023);
        int tag = tags[row];
        float* dst = out + ((long)tag << 10) + col;
        atomicAdd(dst + 0, v.x);
        atomicAdd(dst + 1, v.y);
        atomicAdd(dst + 2, v.z);
        atomicAdd(dst + 3, v.w);
    }
}

extern "C" void kernel_launch(void* const* d_in, const int* in_sizes, int n_in,
                              void* d_out, int out_size, void* d_ws, size_t ws_size,
                              hipStream_t stream) {
    const float* data = (const float*)d_in[0];
    const int* tags = (const int*)d_in[1];
    float* out = (float*)d_out;

    long total = (long)in_sizes[0];   // 33554432
    int n_rows = in_sizes[1];         // 32768

    size_t counts_bytes = (size_t)N_SEG * sizeof(int);                 // 64 KiB
    size_t slots_bytes = (size_t)N_SEG * CAP * sizeof(unsigned short); // 1 MiB
    size_t need = counts_bytes + slots_bytes;

    if (ws_size < need) {
        hipMemsetAsync(d_out, 0, (size_t)out_size * sizeof(float), stream);
        combine_scatter_add<<<2048, 256, 0, stream>>>(data, tags, out, total);
        return;
    }

    int* counts = (int*)d_ws;
    unsigned short* slots = (unsigned short*)((char*)d_ws + counts_bytes);

    hipMemsetAsync(counts, 0, counts_bytes, stream);

    hist_fill<<<(n_rows + 255) / 256, 256, 0, stream>>>(tags, n_rows, counts, slots);

    gather_sum<<<N_SEG, 256, 0, stream>>>(data, tags, counts, slots, out, n_rows);
}